// Round 14
// baseline (153.221 us; speedup 1.0000x reference)
//
#include <hip/hip_runtime.h>
#include <cstddef>

#define EPS_C   1e-5f
#define DELTA_C 0.05f

struct Pairs { int a[6]; int b[6]; int t[6]; };

// ================= device bodies =================

template<int K>
__device__ __forceinline__ void head_body(
    const float* __restrict__ A, const float* __restrict__ W1,
    const float* __restrict__ b1, const float* __restrict__ g,
    const float* __restrict__ bb, float* __restrict__ H,
    float* As, float* rs, float* rs2, int row, int j)
{
  for (int i = j; i < K; i += 256) As[i] = A[row * K + i];
  __syncthreads();

  float a0 = 0.f;
  const float* __restrict__ Wp = W1 + j;
#pragma unroll
  for (int c = 0; c < K; ++c) a0 += As[c] * Wp[(size_t)c * 256];
  float acc = a0 + b1[j];

  rs[j] = acc; rs2[j] = acc * acc;
  __syncthreads();
  for (int st = 128; st > 0; st >>= 1) {
    if (j < st) { rs[j] += rs[j + st]; rs2[j] += rs2[j + st]; }
    __syncthreads();
  }
  float mu  = rs[0] * (1.f / 256.f);
  float var = rs2[0] * (1.f / 256.f) - mu * mu;
  float y = (acc - mu) * rsqrtf(var + EPS_C) * g[j] + bb[j];
  H[row * 256 + j] = fmaxf(y, 0.f);
}

template<int MODE>
__device__ __forceinline__ void skinny_body(
    const float* __restrict__ A, const float* __restrict__ W,
    float* __restrict__ part, int K, int N, int bid, int tid,
    float (*ARs)[64])
{
  int jblocks = N >> 8;
  int jb = bid % jblocks;
  int kc = bid / jblocks;
  int k0 = kc << 6;
  {
    int c = tid >> 6, i = tid & 63;
    int k = k0 + i;
    float v;
    if (MODE == 0) v = A[c * K + k];
    else { int n = k >> 2, df = k & 3; v = A[n * 256 + df * 64 + 60 + c]; }
    ARs[c][i] = v;
  }
  __syncthreads();
  int j = (jb << 8) + tid;
  float acc0 = 0.f, acc1 = 0.f, acc2 = 0.f, acc3 = 0.f;
#pragma unroll
  for (int kk = 0; kk < 64; kk += 16) {
    float w[16];
#pragma unroll
    for (int u = 0; u < 16; ++u) w[u] = W[(size_t)(k0 + kk + u) * N + j];
#pragma unroll
    for (int u = 0; u < 16; ++u) {
      acc0 += ARs[0][kk + u] * w[u];
      acc1 += ARs[1][kk + u] * w[u];
      acc2 += ARs[2][kk + u] * w[u];
      acc3 += ARs[3][kk + u] * w[u];
    }
  }
  part[(size_t)(kc * 4 + 0) * N + j] = acc0;
  part[(size_t)(kc * 4 + 1) * N + j] = acc1;
  part[(size_t)(kc * 4 + 2) * N + j] = acc2;
  part[(size_t)(kc * 4 + 3) * N + j] = acc3;
}

template<int N_, int PARTS>
__device__ __forceinline__ void red_body(
    const float* __restrict__ part, const float* __restrict__ bias,
    const float* __restrict__ g, const float* __restrict__ bb,
    float* __restrict__ out, int c, int tid, float* rs, float* rs2)
{
  constexpr int PER = N_ >> 8;
  float x[PER];
  float s = 0.f, s2 = 0.f;
#pragma unroll
  for (int i = 0; i < PER; ++i) {
    int j = (i << 8) + tid;
    float v = bias[j];
#pragma unroll 8
    for (int p = 0; p < PARTS; ++p) v += part[(size_t)(p * 4 + c) * N_ + j];
    x[i] = v; s += v; s2 += v * v;
  }
  rs[tid] = s; rs2[tid] = s2;
  __syncthreads();
  for (int st = 128; st > 0; st >>= 1) {
    if (tid < st) { rs[tid] += rs[tid + st]; rs2[tid] += rs2[tid + st]; }
    __syncthreads();
  }
  float mu  = rs[0] / (float)N_;
  float var = rs2[0] / (float)N_ - mu * mu;
  float inv = rsqrtf(var + EPS_C);
#pragma unroll
  for (int i = 0; i < PER; ++i) {
    int j = (i << 8) + tid;
    out[c * N_ + j] = fmaxf((x[i] - mu) * inv * g[j] + bb[j], 0.f);
  }
}

// ================= fused launch kernels =================

// K1: head1024 k-partials (0..255) U head8 (256..319) U skinny1 (320..575)
__global__ __launch_bounds__(256) void k1_heads_skinny(
    const float* __restrict__ layer_initial, const float* __restrict__ sW1,
    float* __restrict__ Hp,
    const float* __restrict__ time_features, const float* __restrict__ tW1,
    const float* __restrict__ tb1, const float* __restrict__ t_g,
    const float* __restrict__ t_b, float* __restrict__ Ht,
    const float* __restrict__ observation, const float* __restrict__ fW1,
    float* __restrict__ part1)
{
  __shared__ float As[256];
  __shared__ float rs[256], rs2[256];
  __shared__ float ARs[4][64];
  int bid = blockIdx.x, j = threadIdx.x;
  if (bid < 256) {
    int kc = bid >> 6, row = bid & 63;
    int k0 = kc << 8;
    As[j] = layer_initial[row * 1024 + k0 + j];
    __syncthreads();
    float a0 = 0.f, a1 = 0.f, a2 = 0.f, a3 = 0.f;
    const float* __restrict__ Wp = sW1 + (size_t)k0 * 256 + j;
#pragma unroll 2
    for (int c = 0; c < 256; c += 8) {
      float w0 = Wp[(size_t)(c + 0) * 256];
      float w1 = Wp[(size_t)(c + 1) * 256];
      float w2 = Wp[(size_t)(c + 2) * 256];
      float w3 = Wp[(size_t)(c + 3) * 256];
      float w4 = Wp[(size_t)(c + 4) * 256];
      float w5 = Wp[(size_t)(c + 5) * 256];
      float w6 = Wp[(size_t)(c + 6) * 256];
      float w7 = Wp[(size_t)(c + 7) * 256];
      a0 += As[c + 0] * w0 + As[c + 4] * w4;
      a1 += As[c + 1] * w1 + As[c + 5] * w5;
      a2 += As[c + 2] * w2 + As[c + 6] * w6;
      a3 += As[c + 3] * w3 + As[c + 7] * w7;
    }
    Hp[(size_t)(kc * 64 + row) * 256 + j] = (a0 + a1) + (a2 + a3);
  } else if (bid < 320) {
    head_body<8>(time_features, tW1, tb1, t_g, t_b, Ht, As, rs, rs2, bid - 256, j);
  } else {
    skinny_body<1>(observation, fW1, part1, 4096, 1024, bid - 320, j, ARs);
  }
}

// K2: head1024 reduce+LN -> Hs (blocks 0..63) U red1 (64..67)
__global__ __launch_bounds__(256) void k2_headred_red1(
    const float* __restrict__ Hp, const float* __restrict__ sb1,
    const float* __restrict__ s_g, const float* __restrict__ s_b,
    float* __restrict__ Hs,
    const float* __restrict__ part1, const float* __restrict__ fb1,
    const float* __restrict__ f1g, const float* __restrict__ f1b,
    float* __restrict__ h1)
{
  __shared__ float rs[256], rs2[256];
  int tid = threadIdx.x;
  if (blockIdx.x < 64) {
    int row = blockIdx.x;
    float acc = sb1[tid];
#pragma unroll
    for (int kc = 0; kc < 4; ++kc)
      acc += Hp[(size_t)(kc * 64 + row) * 256 + tid];
    rs[tid] = acc; rs2[tid] = acc * acc;
    __syncthreads();
    for (int st = 128; st > 0; st >>= 1) {
      if (tid < st) { rs[tid] += rs[tid + st]; rs2[tid] += rs2[tid + st]; }
      __syncthreads();
    }
    float mu  = rs[0] * (1.f / 256.f);
    float var = rs2[0] * (1.f / 256.f) - mu * mu;
    float y = (acc - mu) * rsqrtf(var + EPS_C) * s_g[tid] + s_b[tid];
    Hs[row * 256 + tid] = fmaxf(y, 0.f);
  } else {
    red_body<1024, 64>(part1, fb1, f1g, f1b, h1, blockIdx.x - 64, tid, rs, rs2);
  }
}

// K3: emb tiled GEMM (0..255) U skinny2 (256..287)
__global__ __launch_bounds__(256) void k3_emb_skinny(
    const float* __restrict__ Hs, const float* __restrict__ Ht,
    const float* __restrict__ sW2, const float* __restrict__ sb2,
    const float* __restrict__ tW2, const float* __restrict__ tb2,
    float* __restrict__ Vs,
    const float* __restrict__ h1, const float* __restrict__ fW2,
    float* __restrict__ part2)
{
  __shared__ __align__(16) float HcT[64][68];   // [kk][l]
  __shared__ __align__(16) float Wc[64][20];    // [kk][j]
  int tid = threadIdx.x;
  if (blockIdx.x < 256) {
    int n0 = blockIdx.x * 4;
    int lq = tid >> 4, jc = tid & 15;
    int nn = n0 + (jc >> 2), cc = jc & 3;
    int kkw = tid >> 2, nloc = tid & 3;

    float4 hr[4]; float4 wr;
    {
#pragma unroll
      for (int i = 0; i < 4; ++i) {
        int flat = i * 1024 + tid * 4;
        int l = flat >> 6, kk = flat & 63;
        hr[i] = *(const float4*)&Hs[l * 256 + kk];
      }
      wr = *(const float4*)&sW2[(size_t)kkw * 65536 + (size_t)(n0 + nloc) * 64 + 60];
    }
    float acc0 = 0.f, acc1 = 0.f, acc2 = 0.f, acc3 = 0.f;
    for (int ch = 0; ch < 8; ++ch) {
      __syncthreads();
#pragma unroll
      for (int i = 0; i < 4; ++i) {
        int flat = i * 1024 + tid * 4;
        int l = flat >> 6, kk = flat & 63;
        HcT[kk + 0][l] = hr[i].x;
        HcT[kk + 1][l] = hr[i].y;
        HcT[kk + 2][l] = hr[i].z;
        HcT[kk + 3][l] = hr[i].w;
      }
      *(float4*)&Wc[kkw][nloc * 4] = wr;
      __syncthreads();
      if (ch < 7) {
        int nc2 = ch + 1;
        const float* __restrict__ Hsrc = (nc2 < 4) ? Hs : Ht;
        const float* __restrict__ Wsrc = (nc2 < 4) ? sW2 : tW2;
        int kl = (nc2 & 3) << 6;
#pragma unroll
        for (int i = 0; i < 4; ++i) {
          int flat = i * 1024 + tid * 4;
          int l = flat >> 6, kk = flat & 63;
          hr[i] = *(const float4*)&Hsrc[l * 256 + kl + kk];
        }
        wr = *(const float4*)&Wsrc[(size_t)(kl + kkw) * 65536 + (size_t)(n0 + nloc) * 64 + 60];
      }
#pragma unroll 8
      for (int kk = 0; kk < 64; ++kk) {
        float4 av = *(const float4*)&HcT[kk][lq * 4];
        float w = Wc[kk][jc];
        acc0 += av.x * w; acc1 += av.y * w; acc2 += av.z * w; acc3 += av.w * w;
      }
    }
    int jj = nn * 64 + 60 + cc;
    float bias = sb2[jj] + tb2[jj];
    float4 st = { acc0 + bias, acc1 + bias, acc2 + bias, acc3 + bias };
    *(float4*)&Vs[(size_t)cc * 65536 + (size_t)nn * 64 + lq * 4] = st;
  } else {
    skinny_body<0>(h1, fW2, part2, 1024, 512, blockIdx.x - 256, tid,
                   (float(*)[64])&HcT[0][0]);
  }
}

// K4: red2 -> h2 (blocks 0..3) U vab + VsT transpose (4..67)
__global__ __launch_bounds__(256) void k4_red2_vab(
    const float* __restrict__ part2, const float* __restrict__ fb2,
    const float* __restrict__ f2g, const float* __restrict__ f2b,
    float* __restrict__ h2,
    const float* __restrict__ Vs, const float* __restrict__ Bmat,
    float* __restrict__ VaBt, float* __restrict__ VsT)
{
  __shared__ float Va[64][65], Bs[64][65];
  int tid = threadIdx.x;
  if (blockIdx.x < 4) {
    red_body<512, 16>(part2, fb2, f2g, f2b, h2, blockIdx.x, tid,
                      &Va[0][0], &Bs[0][0]);
  } else {
    int bid = blockIdx.x - 4;
    int c = bid >> 4, nb = bid & 15;
    int n0 = nb << 6;
    int rg = tid >> 4, cg = tid & 15;
#pragma unroll
    for (int i = 0; i < 4; ++i) {
      int flat = i * 1024 + tid * 4;
      int rr = flat >> 6, cc = flat & 63;
      float4 v = *(const float4*)&Vs[(size_t)c * 65536 + (size_t)(n0 + rr) * 64 + cc];
      Va[rr][cc] = v.x; Va[rr][cc+1] = v.y; Va[rr][cc+2] = v.z; Va[rr][cc+3] = v.w;
      float4 w = *(const float4*)&Bmat[flat];
      Bs[rr][cc] = w.x; Bs[rr][cc+1] = w.y; Bs[rr][cc+2] = w.z; Bs[rr][cc+3] = w.w;
    }
    __syncthreads();
#pragma unroll
    for (int i = 0; i < 4; ++i) {
      int flat = i * 1024 + tid * 4;
      int l = flat >> 6, nn = flat & 63;
      float4 st = { Va[nn][l], Va[nn+1][l], Va[nn+2][l], Va[nn+3][l] };
      *(float4*)&VsT[(size_t)c * 65536 + (size_t)l * 1024 + n0 + nn] = st;
    }
    float acc[4][4];
#pragma unroll
    for (int i = 0; i < 4; ++i)
#pragma unroll
      for (int j = 0; j < 4; ++j) acc[i][j] = 0.f;
#pragma unroll 4
    for (int l = 0; l < 64; ++l) {
      float av[4], bv[4];
#pragma unroll
      for (int i = 0; i < 4; ++i) av[i] = Va[rg * 4 + i][l];
#pragma unroll
      for (int j = 0; j < 4; ++j) bv[j] = Bs[l][cg * 4 + j];
#pragma unroll
      for (int i = 0; i < 4; ++i)
#pragma unroll
        for (int j = 0; j < 4; ++j) acc[i][j] += av[i] * bv[j];
    }
#pragma unroll
    for (int j = 0; j < 4; ++j) {
      float4 st = { acc[0][j], acc[1][j], acc[2][j], acc[3][j] };
      *(float4*)&VaBt[(size_t)c * 65536 + (size_t)(cg * 4 + j) * 1024 + n0 + rg * 4] = st;
    }
  }
}

// K5: big_w3 (h2 read from global, 2-way k-split)
__global__ __launch_bounds__(256) void big_w3c(
    const float* __restrict__ h2, const float* __restrict__ fW3,
    const float* __restrict__ fb3, float* __restrict__ Xr)
{
  int tid = threadIdx.x;
  __shared__ float h2s[2048];
  __shared__ float sm[4][128];
  for (int i = tid; i < 2048; i += 256) h2s[i] = h2[i];
  int col = tid & 127, ks = tid >> 7;
  int j = blockIdx.x * 128 + col;
  int kbase = ks << 8;
  __syncthreads();
  float acc0 = 0.f, acc1 = 0.f, acc2 = 0.f, acc3 = 0.f;
  for (int k0 = 0; k0 < 256; k0 += 16) {
    float w[16];
#pragma unroll
    for (int u = 0; u < 16; ++u) w[u] = fW3[(size_t)(kbase + k0 + u) * 65536 + j];
#pragma unroll
    for (int u = 0; u < 16; ++u) {
      int k = kbase + k0 + u;
      acc0 += h2s[k]        * w[u];
      acc1 += h2s[512 + k]  * w[u];
      acc2 += h2s[1024 + k] * w[u];
      acc3 += h2s[1536 + k] * w[u];
    }
  }
  if (ks) { sm[0][col] = acc0; sm[1][col] = acc1; sm[2][col] = acc2; sm[3][col] = acc3; }
  __syncthreads();
  if (!ks) {
    float b = fb3[j];
    Xr[j]            = acc0 + sm[0][col] + b;
    Xr[65536 + j]    = acc1 + sm[1][col] + b;
    Xr[131072 + j]   = acc2 + sm[2][col] + b;
    Xr[196608 + j]   = acc3 + sm[3][col] + b;
  }
}

// split-flash attention partial; register softmax, E aliases VbT,
// X read directly from global (L2) with 2-deep register pipeline.
// LDS = 34.8 KB -> 4 blocks/CU (16 waves/CU).
template<int NSPLIT>
__global__ __launch_bounds__(256) void attn_partial(
    const float* __restrict__ VaBt, const float* __restrict__ VsT,
    const float* __restrict__ Xbase, float* __restrict__ Pl,
    float* __restrict__ ml, Pairs pr)
{
  constexpr int TILES = 16 / NSPLIT;
  int pi  = blockIdx.x / (16 * NSPLIT);
  int rem = blockIdx.x % (16 * NSPLIT);
  int nb  = rem / NSPLIT;
  int s   = rem % NSPLIT;
  int n0  = nb << 6;
  int tid = threadIdx.x;
  int rg = tid >> 4, cg = tid & 15;
  int rg4 = rg * 4, cg4 = cg * 4;
  int a = pr.a[pi], b = pr.b[pi], t = pr.t[pi];

  __shared__ __align__(16) float VaT[64][68];
  __shared__ __align__(16) float VbT[64][68];
  float (*St)[68] = VbT;

#pragma unroll
  for (int i = 0; i < 4; ++i) {
    int flat = i * 1024 + tid * 4;
    int p = flat >> 6, nn = flat & 63;
    float4 v = *(const float4*)&VaBt[(size_t)a * 65536 + (size_t)p * 1024 + n0 + nn];
    *(float4*)&VaT[p][nn] = v;
  }
  float m_run[4], l_run[4];
#pragma unroll
  for (int i = 0; i < 4; ++i) { m_run[i] = -1e30f; l_run[i] = 0.f; }
  float P[4][4];
#pragma unroll
  for (int i = 0; i < 4; ++i)
#pragma unroll
    for (int j = 0; j < 4; ++j) P[i][j] = 0.f;
  __syncthreads();

  for (int ti = 0; ti < TILES; ++ti) {
    int q0 = (s * TILES + ti) << 6;
    const float* __restrict__ Xt = Xbase + (size_t)t * 65536 + (size_t)q0 * 64;
    if (ti) __syncthreads();
#pragma unroll
    for (int i = 0; i < 4; ++i) {
      int flat = i * 1024 + tid * 4;
      int p = flat >> 6, qq = flat & 63;
      float4 v = *(const float4*)&VsT[(size_t)b * 65536 + (size_t)p * 1024 + q0 + qq];
      *(float4*)&VbT[p][qq] = v;
    }
    __syncthreads();
    float sa[4][4];
#pragma unroll
    for (int i = 0; i < 4; ++i)
#pragma unroll
      for (int j = 0; j < 4; ++j) sa[i][j] = 0.f;
#pragma unroll 4
    for (int p = 0; p < 64; ++p) {
      float av[4], bv[4];
      *(float4*)av = *(const float4*)&VaT[p][rg4];
      *(float4*)bv = *(const float4*)&VbT[p][cg4];
#pragma unroll
      for (int i = 0; i < 4; ++i)
#pragma unroll
        for (int j = 0; j < 4; ++j) sa[i][j] += av[i] * bv[j];
    }
    float scv[4];
#pragma unroll
    for (int i = 0; i < 4; ++i) {
#pragma unroll
      for (int j = 0; j < 4; ++j) sa[i][j] = (sa[i][j] >= DELTA_C) ? sa[i][j] : 0.f;
      float tm = fmaxf(fmaxf(sa[i][0], sa[i][1]), fmaxf(sa[i][2], sa[i][3]));
      tm = fmaxf(tm, __shfl_xor(tm, 1));
      tm = fmaxf(tm, __shfl_xor(tm, 2));
      tm = fmaxf(tm, __shfl_xor(tm, 4));
      tm = fmaxf(tm, __shfl_xor(tm, 8));
      float mnew = fmaxf(m_run[i], tm);
      float sc = __expf(m_run[i] - mnew);
      float ssum = 0.f;
#pragma unroll
      for (int j = 0; j < 4; ++j) {
        float e = __expf(sa[i][j] - mnew);
        sa[i][j] = e;
        ssum += e;
      }
      ssum += __shfl_xor(ssum, 1);
      ssum += __shfl_xor(ssum, 2);
      ssum += __shfl_xor(ssum, 4);
      ssum += __shfl_xor(ssum, 8);
      l_run[i] = l_run[i] * sc + ssum;
      m_run[i] = mnew;
      scv[i] = sc;
    }
    __syncthreads();   // S-GEMM reads of VbT done before E overwrite
#pragma unroll
    for (int i = 0; i < 4; ++i) {
      float4 e4 = { sa[i][0], sa[i][1], sa[i][2], sa[i][3] };
      *(float4*)&St[rg4 + i][cg4] = e4;
    }
    __syncthreads();   // E visible
    // rescale + PV; X via global with 2-deep prefetch pipeline
#pragma unroll
    for (int i = 0; i < 4; ++i)
#pragma unroll
      for (int j = 0; j < 4; ++j) P[i][j] *= scv[i];
    float4 xc[4];
#pragma unroll
    for (int u = 0; u < 4; ++u)
      xc[u] = *(const float4*)&Xt[(size_t)u * 64 + cg4];
    for (int q4 = 0; q4 < 64; q4 += 4) {
      float4 xn[4];
      if (q4 < 60) {
#pragma unroll
        for (int u = 0; u < 4; ++u)
          xn[u] = *(const float4*)&Xt[(size_t)(q4 + 4 + u) * 64 + cg4];
      }
      float4 ev[4];
#pragma unroll
      for (int i = 0; i < 4; ++i) ev[i] = *(const float4*)&St[rg4 + i][q4];
#pragma unroll
      for (int i = 0; i < 4; ++i) {
        const float* e = &ev[i].x;
#pragma unroll
        for (int u = 0; u < 4; ++u) {
          const float* x = &xc[u].x;
#pragma unroll
          for (int j = 0; j < 4; ++j) P[i][j] += e[u] * x[j];
        }
      }
#pragma unroll
      for (int u = 0; u < 4; ++u) xc[u] = xn[u];
    }
  }
  size_t base = (size_t)((pi * 16 + nb) * NSPLIT + s);
  float* pp = Pl + base * 4096;
#pragma unroll
  for (int i = 0; i < 4; ++i) {
    float4 st = { P[i][0], P[i][1], P[i][2], P[i][3] };
    *(float4*)&pp[(size_t)(rg4 + i) * 64 + cg4] = st;
  }
  if ((tid & 15) == 0) {
    float* mlp = ml + base * 128;
#pragma unroll
    for (int i = 0; i < 4; ++i) {
      mlp[rg4 + i]      = m_run[i];
      mlp[64 + rg4 + i] = l_run[i];
    }
  }
}

// merge: block = (mm, nb, n-quarter, inst); 16 rows each -> Gp
template<int NS_T>
__global__ __launch_bounds__(256) void merge_partial16(
    const float* __restrict__ Pl, const float* __restrict__ ml,
    const float* __restrict__ Wf, const float* __restrict__ Wb,
    float* __restrict__ Gp)
{
  int mm  = blockIdx.x / 192;
  int rem = blockIdx.x % 192;
  int nb  = rem / 12;
  int r2  = rem % 12;
  int nq  = r2 / 3, inst = r2 % 3;
  int tid = threadIdx.x;
  int r = tid >> 4, fq = tid & 15;

  __shared__ __align__(16) float Ps[16][68];   // [r][f]
  __shared__ __align__(16) float Wt[64][68];   // [f][out]

  size_t base = (size_t)((mm * 3 + inst) * 16 + nb) * NS_T;
  const float* mlp = ml + base * 128;
  int rowi = nq * 16 + r;
  float mg = -1e30f;
#pragma unroll
  for (int s2 = 0; s2 < NS_T; ++s2) mg = fmaxf(mg, mlp[s2 * 128 + rowi]);
  float acc[4] = {0.f, 0.f, 0.f, 0.f};
  float lg = 0.f;
#pragma unroll
  for (int s2 = 0; s2 < NS_T; ++s2) {
    float f = __expf(mlp[s2 * 128 + rowi] - mg);
    lg += f * mlp[s2 * 128 + 64 + rowi];
    float4 v = *(const float4*)(Pl + (base + s2) * 4096 + rowi * 64 + fq * 4);
    acc[0] += f * v.x; acc[1] += f * v.y; acc[2] += f * v.z; acc[3] += f * v.w;
  }
  float inv = 1.f / lg;
  float4 pv = { acc[0] * inv, acc[1] * inv, acc[2] * inv, acc[3] * inv };
  *(float4*)&Ps[r][fq * 4] = pv;
  for (int i = tid; i < 4096; i += 256) {
    int rr = i >> 6, cc = i & 63;
    float w;
    if (inst == 0)      w = Wf[i] + Wb[i];
    else if (inst == 1) w = Wf[4096 + i];
    else                w = Wb[4096 + i];
    Wt[rr][cc] = w;
  }
  __syncthreads();
  float g0 = 0.f, g1 = 0.f, g2 = 0.f, g3 = 0.f;
#pragma unroll 8
  for (int f = 0; f < 64; ++f) {
    float p = Ps[r][f];
    float4 w4 = *(const float4*)&Wt[f][fq * 4];
    g0 += p * w4.x; g1 += p * w4.y; g2 += p * w4.z; g3 += p * w4.w;
  }
  float4 st = { g0, g1, g2, g3 };
  *(float4*)&Gp[(size_t)(mm * 3 + inst) * 65536 +
                (size_t)(nb * 64 + nq * 16 + r) * 64 + fq * 4] = st;
}

// Z = tanh(G0+b) + tanh(G1+G2+b)
__global__ __launch_bounds__(256) void finalize_z(
    const float* __restrict__ Gp, const float* __restrict__ bconv,
    float* __restrict__ dst0, float* __restrict__ dst1, float* __restrict__ extra1)
{
  int mm = blockIdx.x >> 4;
  int nb = blockIdx.x & 15;
  int tid = threadIdx.x;
  size_t tileOff = (size_t)(nb << 6) * 64;
  const float* g0 = Gp + (size_t)(mm * 3 + 0) * 65536 + tileOff;
  const float* g1 = Gp + (size_t)(mm * 3 + 1) * 65536 + tileOff;
  const float* g2 = Gp + (size_t)(mm * 3 + 2) * 65536 + tileOff;
  float* dst = (mm == 0) ? dst0 : dst1;
  for (int i = tid * 4; i < 4096; i += 1024) {
    float4 a = *(const float4*)&g0[i];
    float4 b = *(const float4*)&g1[i];
    float4 c = *(const float4*)&g2[i];
    int col = i & 63;
    float4 z;
    z.x = tanhf(a.x + bconv[col+0]) + tanhf(b.x + c.x + bconv[col+0]);
    z.y = tanhf(a.y + bconv[col+1]) + tanhf(b.y + c.y + bconv[col+1]);
    z.z = tanhf(a.z + bconv[col+2]) + tanhf(b.z + c.z + bconv[col+2]);
    z.w = tanhf(a.w + bconv[col+3]) + tanhf(b.w + c.w + bconv[col+3]);
    *(float4*)&dst[tileOff + i] = z;
    if (mm == 1 && extra1) *(float4*)&extra1[tileOff + i] = z;
  }
}

extern "C" void kernel_launch(void* const* d_in, const int* in_sizes, int n_in,
                              void* d_out, int out_size, void* d_ws, size_t ws_size,
                              hipStream_t stream)
{
  const float* observation   = (const float*)d_in[0];
  const float* time_features = (const float*)d_in[1];
  const float* layer_initial = (const float*)d_in[2];
  const float* sW1   = (const float*)d_in[3];
  const float* sb1   = (const float*)d_in[4];
  const float* s_ln_g = (const float*)d_in[5];
  const float* s_ln_b = (const float*)d_in[6];
  const float* sW2   = (const float*)d_in[7];
  const float* sb2   = (const float*)d_in[8];
  const float* tW1   = (const float*)d_in[9];
  const float* tb1   = (const float*)d_in[10];
  const float* t_ln_g = (const float*)d_in[11];
  const float* t_ln_b = (const float*)d_in[12];
  const float* tW2   = (const float*)d_in[13];
  const float* tb2   = (const float*)d_in[14];
  const float* Bmat  = (const float*)d_in[15];
  const float* fW1   = (const float*)d_in[16];
  const float* fb1   = (const float*)d_in[17];
  const float* f1g   = (const float*)d_in[18];
  const float* f1b   = (const float*)d_in[19];
  const float* fW2   = (const float*)d_in[20];
  const float* fb2   = (const float*)d_in[21];
  const float* f2g   = (const float*)d_in[22];
  const float* f2b   = (const float*)d_in[23];
  const float* fW3   = (const float*)d_in[24];
  const float* fb3   = (const float*)d_in[25];
  const float* Wf    = (const float*)d_in[26];
  const float* Wb    = (const float*)d_in[27];
  const float* bconv = (const float*)d_in[28];
  float* out = (float*)d_out;

  float* ws    = (float*)d_ws;
  float* Hs    = ws;                  // 16384
  float* Ht    = Hs    + 16384;       // 16384
  float* Hp    = Ht    + 16384;       // 65536
  float* Vs    = Hp    + 65536;       // 262144
  float* VsT   = Vs    + 262144;      // 262144
  float* VaBt  = VsT   + 262144;      // 262144
  float* part1 = VaBt  + 262144;      // 262144
  float* part2 = part1 + 262144;      // 32768
  float* h1    = part2 + 32768;       // 4096
  float* h2    = h1    + 4096;        // 2048
  float* Xr    = h2    + 2048;        // 262144
  float* Pl    = Xr    + 262144;      // 3,145,728 (L1, NS=8)
  float* ml    = Pl    + 3145728;     // 98,304
  float* Pl2   = ml    + 98304;       // 3,145,728 (L2, NS=16)
  float* ml2   = Pl2   + 3145728;     // 98,304
  float* Z1    = ml2   + 98304;       // 131072
  float* Gp    = Z1    + 131072;      // 393216 (6 x 65536)

  k1_heads_skinny<<<576, 256, 0, stream>>>(
      layer_initial, sW1, Hp,
      time_features, tW1, tb1, t_ln_g, t_ln_b, Ht,
      observation, fW1, part1);
  k2_headred_red1<<<68, 256, 0, stream>>>(
      Hp, sb1, s_ln_g, s_ln_b, Hs,
      part1, fb1, f1g, f1b, h1);
  k3_emb_skinny<<<288, 256, 0, stream>>>(
      Hs, Ht, sW2, sb2, tW2, tb2, Vs, h1, fW2, part2);
  k4_red2_vab<<<68, 256, 0, stream>>>(
      part2, fb2, f2g, f2b, h2, Vs, Bmat, VaBt, VsT);
  big_w3c<<<512, 256, 0, stream>>>(h2, fW3, fb3, Xr);

  // layer-1, m=30 (cols 60/61, X rows 0/1) and m=31 (cols 62/63, X rows 2/3)
  Pairs pA;
  pA.a[0]=1; pA.b[0]=1; pA.t[0]=1;   // k=0, m=30: A(61,61) @ X[61]
  pA.a[1]=0; pA.b[1]=1; pA.t[1]=0;   // k=1, m=30: A(60,61) @ X[60]
  pA.a[2]=1; pA.b[2]=0; pA.t[2]=0;   // k=1, m=30: A(61,60) @ X[60]
  pA.a[3]=3; pA.b[3]=3; pA.t[3]=3;   // k=0, m=31: A(63,63) @ X[63]
  pA.a[4]=2; pA.b[4]=3; pA.t[4]=2;   // k=1, m=31: A(62,63) @ X[62]
  pA.a[5]=3; pA.b[5]=2; pA.t[5]=2;   // k=1, m=31: A(63,62) @ X[62]
  attn_partial<8><<<6 * 16 * 8, 256, 0, stream>>>(VaBt, VsT, Xr, Pl, ml, pA);
  merge_partial16<8><<<384, 256, 0, stream>>>(Pl, ml, Wf, Wb, Gp);
  finalize_z<<<32, 256, 0, stream>>>(Gp, bconv, Z1, Z1 + 65536, out);

  // layer-2, m=15: cols 62(=2)/60(=0), X = Z1 rows {0: m30, 1: m31}; NS=16
  Pairs pB;
  pB.a[0]=2; pB.b[0]=2; pB.t[0]=1;   // k=0: A(62,62) @ X1[31]
  pB.a[1]=0; pB.b[1]=2; pB.t[1]=0;   // k=1: A(60,62) @ X1[30]
  pB.a[2]=2; pB.b[2]=0; pB.t[2]=0;   // k=1: A(62,60) @ X1[30]
  pB.a[3]=pB.a[4]=pB.a[5]=0; pB.b[3]=pB.b[4]=pB.b[5]=0; pB.t[3]=pB.t[4]=pB.t[5]=0;
  attn_partial<16><<<3 * 16 * 16, 256, 0, stream>>>(VaBt, VsT, Z1, Pl2, ml2, pB);
  merge_partial16<16><<<192, 256, 0, stream>>>(Pl2, ml2, Wf, Wb, Gp);
  finalize_z<<<16, 256, 0, stream>>>(Gp, bconv, out + 65536, nullptr, nullptr);
}

// Round 15
// 150.438 us; speedup vs baseline: 1.0185x; 1.0185x over previous
//
#include <hip/hip_runtime.h>
#include <cstddef>

#define EPS_C   1e-5f
#define DELTA_C 0.05f

struct Pairs { int a[6]; int b[6]; int t[6]; };

// ================= device bodies =================

template<int K>
__device__ __forceinline__ void head_body(
    const float* __restrict__ A, const float* __restrict__ W1,
    const float* __restrict__ b1, const float* __restrict__ g,
    const float* __restrict__ bb, float* __restrict__ H,
    float* As, float* rs, float* rs2, int row, int j)
{
  for (int i = j; i < K; i += 256) As[i] = A[row * K + i];
  __syncthreads();

  float a0 = 0.f;
  const float* __restrict__ Wp = W1 + j;
#pragma unroll
  for (int c = 0; c < K; ++c) a0 += As[c] * Wp[(size_t)c * 256];
  float acc = a0 + b1[j];

  rs[j] = acc; rs2[j] = acc * acc;
  __syncthreads();
  for (int st = 128; st > 0; st >>= 1) {
    if (j < st) { rs[j] += rs[j + st]; rs2[j] += rs2[j + st]; }
    __syncthreads();
  }
  float mu  = rs[0] * (1.f / 256.f);
  float var = rs2[0] * (1.f / 256.f) - mu * mu;
  float y = (acc - mu) * rsqrtf(var + EPS_C) * g[j] + bb[j];
  H[row * 256 + j] = fmaxf(y, 0.f);
}

template<int MODE>
__device__ __forceinline__ void skinny_body(
    const float* __restrict__ A, const float* __restrict__ W,
    float* __restrict__ part, int K, int N, int bid, int tid,
    float (*ARs)[64])
{
  int jblocks = N >> 8;
  int jb = bid % jblocks;
  int kc = bid / jblocks;
  int k0 = kc << 6;
  {
    int c = tid >> 6, i = tid & 63;
    int k = k0 + i;
    float v;
    if (MODE == 0) v = A[c * K + k];
    else { int n = k >> 2, df = k & 3; v = A[n * 256 + df * 64 + 60 + c]; }
    ARs[c][i] = v;
  }
  __syncthreads();
  int j = (jb << 8) + tid;
  float acc0 = 0.f, acc1 = 0.f, acc2 = 0.f, acc3 = 0.f;
#pragma unroll
  for (int kk = 0; kk < 64; kk += 16) {
    float w[16];
#pragma unroll
    for (int u = 0; u < 16; ++u) w[u] = W[(size_t)(k0 + kk + u) * N + j];
#pragma unroll
    for (int u = 0; u < 16; ++u) {
      acc0 += ARs[0][kk + u] * w[u];
      acc1 += ARs[1][kk + u] * w[u];
      acc2 += ARs[2][kk + u] * w[u];
      acc3 += ARs[3][kk + u] * w[u];
    }
  }
  part[(size_t)(kc * 4 + 0) * N + j] = acc0;
  part[(size_t)(kc * 4 + 1) * N + j] = acc1;
  part[(size_t)(kc * 4 + 2) * N + j] = acc2;
  part[(size_t)(kc * 4 + 3) * N + j] = acc3;
}

template<int N_, int PARTS>
__device__ __forceinline__ void red_body(
    const float* __restrict__ part, const float* __restrict__ bias,
    const float* __restrict__ g, const float* __restrict__ bb,
    float* __restrict__ out, int c, int tid, float* rs, float* rs2)
{
  constexpr int PER = N_ >> 8;
  float x[PER];
  float s = 0.f, s2 = 0.f;
#pragma unroll
  for (int i = 0; i < PER; ++i) {
    int j = (i << 8) + tid;
    float v = bias[j];
#pragma unroll 8
    for (int p = 0; p < PARTS; ++p) v += part[(size_t)(p * 4 + c) * N_ + j];
    x[i] = v; s += v; s2 += v * v;
  }
  rs[tid] = s; rs2[tid] = s2;
  __syncthreads();
  for (int st = 128; st > 0; st >>= 1) {
    if (tid < st) { rs[tid] += rs[tid + st]; rs2[tid] += rs2[tid + st]; }
    __syncthreads();
  }
  float mu  = rs[0] / (float)N_;
  float var = rs2[0] / (float)N_ - mu * mu;
  float inv = rsqrtf(var + EPS_C);
#pragma unroll
  for (int i = 0; i < PER; ++i) {
    int j = (i << 8) + tid;
    out[c * N_ + j] = fmaxf((x[i] - mu) * inv * g[j] + bb[j], 0.f);
  }
}

// ================= fused launch kernels =================

// K1: head1024 k-partials (0..255) U head8 (256..319) U skinny1 (320..575)
__global__ __launch_bounds__(256) void k1_heads_skinny(
    const float* __restrict__ layer_initial, const float* __restrict__ sW1,
    float* __restrict__ Hp,
    const float* __restrict__ time_features, const float* __restrict__ tW1,
    const float* __restrict__ tb1, const float* __restrict__ t_g,
    const float* __restrict__ t_b, float* __restrict__ Ht,
    const float* __restrict__ observation, const float* __restrict__ fW1,
    float* __restrict__ part1)
{
  __shared__ float As[256];
  __shared__ float rs[256], rs2[256];
  __shared__ float ARs[4][64];
  int bid = blockIdx.x, j = threadIdx.x;
  if (bid < 256) {
    int kc = bid >> 6, row = bid & 63;
    int k0 = kc << 8;
    As[j] = layer_initial[row * 1024 + k0 + j];
    __syncthreads();
    float a0 = 0.f, a1 = 0.f, a2 = 0.f, a3 = 0.f;
    const float* __restrict__ Wp = sW1 + (size_t)k0 * 256 + j;
#pragma unroll 2
    for (int c = 0; c < 256; c += 8) {
      float w0 = Wp[(size_t)(c + 0) * 256];
      float w1 = Wp[(size_t)(c + 1) * 256];
      float w2 = Wp[(size_t)(c + 2) * 256];
      float w3 = Wp[(size_t)(c + 3) * 256];
      float w4 = Wp[(size_t)(c + 4) * 256];
      float w5 = Wp[(size_t)(c + 5) * 256];
      float w6 = Wp[(size_t)(c + 6) * 256];
      float w7 = Wp[(size_t)(c + 7) * 256];
      a0 += As[c + 0] * w0 + As[c + 4] * w4;
      a1 += As[c + 1] * w1 + As[c + 5] * w5;
      a2 += As[c + 2] * w2 + As[c + 6] * w6;
      a3 += As[c + 3] * w3 + As[c + 7] * w7;
    }
    Hp[(size_t)(kc * 64 + row) * 256 + j] = (a0 + a1) + (a2 + a3);
  } else if (bid < 320) {
    head_body<8>(time_features, tW1, tb1, t_g, t_b, Ht, As, rs, rs2, bid - 256, j);
  } else {
    skinny_body<1>(observation, fW1, part1, 4096, 1024, bid - 320, j, ARs);
  }
}

// K2: head1024 reduce+LN -> Hs (blocks 0..63) U red1 (64..67)
__global__ __launch_bounds__(256) void k2_headred_red1(
    const float* __restrict__ Hp, const float* __restrict__ sb1,
    const float* __restrict__ s_g, const float* __restrict__ s_b,
    float* __restrict__ Hs,
    const float* __restrict__ part1, const float* __restrict__ fb1,
    const float* __restrict__ f1g, const float* __restrict__ f1b,
    float* __restrict__ h1)
{
  __shared__ float rs[256], rs2[256];
  int tid = threadIdx.x;
  if (blockIdx.x < 64) {
    int row = blockIdx.x;
    float acc = sb1[tid];
#pragma unroll
    for (int kc = 0; kc < 4; ++kc)
      acc += Hp[(size_t)(kc * 64 + row) * 256 + tid];
    rs[tid] = acc; rs2[tid] = acc * acc;
    __syncthreads();
    for (int st = 128; st > 0; st >>= 1) {
      if (tid < st) { rs[tid] += rs[tid + st]; rs2[tid] += rs2[tid + st]; }
      __syncthreads();
    }
    float mu  = rs[0] * (1.f / 256.f);
    float var = rs2[0] * (1.f / 256.f) - mu * mu;
    float y = (acc - mu) * rsqrtf(var + EPS_C) * s_g[tid] + s_b[tid];
    Hs[row * 256 + tid] = fmaxf(y, 0.f);
  } else {
    red_body<1024, 64>(part1, fb1, f1g, f1b, h1, blockIdx.x - 64, tid, rs, rs2);
  }
}

// K3: emb tiled GEMM (0..255) U skinny2 (256..287)
__global__ __launch_bounds__(256) void k3_emb_skinny(
    const float* __restrict__ Hs, const float* __restrict__ Ht,
    const float* __restrict__ sW2, const float* __restrict__ sb2,
    const float* __restrict__ tW2, const float* __restrict__ tb2,
    float* __restrict__ Vs,
    const float* __restrict__ h1, const float* __restrict__ fW2,
    float* __restrict__ part2)
{
  __shared__ __align__(16) float HcT[64][68];   // [kk][l]
  __shared__ __align__(16) float Wc[64][20];    // [kk][j]
  int tid = threadIdx.x;
  if (blockIdx.x < 256) {
    int n0 = blockIdx.x * 4;
    int lq = tid >> 4, jc = tid & 15;
    int nn = n0 + (jc >> 2), cc = jc & 3;
    int kkw = tid >> 2, nloc = tid & 3;

    float4 hr[4]; float4 wr;
    {
#pragma unroll
      for (int i = 0; i < 4; ++i) {
        int flat = i * 1024 + tid * 4;
        int l = flat >> 6, kk = flat & 63;
        hr[i] = *(const float4*)&Hs[l * 256 + kk];
      }
      wr = *(const float4*)&sW2[(size_t)kkw * 65536 + (size_t)(n0 + nloc) * 64 + 60];
    }
    float acc0 = 0.f, acc1 = 0.f, acc2 = 0.f, acc3 = 0.f;
    for (int ch = 0; ch < 8; ++ch) {
      __syncthreads();
#pragma unroll
      for (int i = 0; i < 4; ++i) {
        int flat = i * 1024 + tid * 4;
        int l = flat >> 6, kk = flat & 63;
        HcT[kk + 0][l] = hr[i].x;
        HcT[kk + 1][l] = hr[i].y;
        HcT[kk + 2][l] = hr[i].z;
        HcT[kk + 3][l] = hr[i].w;
      }
      *(float4*)&Wc[kkw][nloc * 4] = wr;
      __syncthreads();
      if (ch < 7) {
        int nc2 = ch + 1;
        const float* __restrict__ Hsrc = (nc2 < 4) ? Hs : Ht;
        const float* __restrict__ Wsrc = (nc2 < 4) ? sW2 : tW2;
        int kl = (nc2 & 3) << 6;
#pragma unroll
        for (int i = 0; i < 4; ++i) {
          int flat = i * 1024 + tid * 4;
          int l = flat >> 6, kk = flat & 63;
          hr[i] = *(const float4*)&Hsrc[l * 256 + kl + kk];
        }
        wr = *(const float4*)&Wsrc[(size_t)(kl + kkw) * 65536 + (size_t)(n0 + nloc) * 64 + 60];
      }
#pragma unroll 8
      for (int kk = 0; kk < 64; ++kk) {
        float4 av = *(const float4*)&HcT[kk][lq * 4];
        float w = Wc[kk][jc];
        acc0 += av.x * w; acc1 += av.y * w; acc2 += av.z * w; acc3 += av.w * w;
      }
    }
    int jj = nn * 64 + 60 + cc;
    float bias = sb2[jj] + tb2[jj];
    float4 st = { acc0 + bias, acc1 + bias, acc2 + bias, acc3 + bias };
    *(float4*)&Vs[(size_t)cc * 65536 + (size_t)nn * 64 + lq * 4] = st;
  } else {
    skinny_body<0>(h1, fW2, part2, 1024, 512, blockIdx.x - 256, tid,
                   (float(*)[64])&HcT[0][0]);
  }
}

// K4: red2 -> h2 (blocks 0..3) U vab + VsT transpose (4..67)
__global__ __launch_bounds__(256) void k4_red2_vab(
    const float* __restrict__ part2, const float* __restrict__ fb2,
    const float* __restrict__ f2g, const float* __restrict__ f2b,
    float* __restrict__ h2,
    const float* __restrict__ Vs, const float* __restrict__ Bmat,
    float* __restrict__ VaBt, float* __restrict__ VsT)
{
  __shared__ float Va[64][65], Bs[64][65];
  int tid = threadIdx.x;
  if (blockIdx.x < 4) {
    red_body<512, 16>(part2, fb2, f2g, f2b, h2, blockIdx.x, tid,
                      &Va[0][0], &Bs[0][0]);
  } else {
    int bid = blockIdx.x - 4;
    int c = bid >> 4, nb = bid & 15;
    int n0 = nb << 6;
    int rg = tid >> 4, cg = tid & 15;
#pragma unroll
    for (int i = 0; i < 4; ++i) {
      int flat = i * 1024 + tid * 4;
      int rr = flat >> 6, cc = flat & 63;
      float4 v = *(const float4*)&Vs[(size_t)c * 65536 + (size_t)(n0 + rr) * 64 + cc];
      Va[rr][cc] = v.x; Va[rr][cc+1] = v.y; Va[rr][cc+2] = v.z; Va[rr][cc+3] = v.w;
      float4 w = *(const float4*)&Bmat[flat];
      Bs[rr][cc] = w.x; Bs[rr][cc+1] = w.y; Bs[rr][cc+2] = w.z; Bs[rr][cc+3] = w.w;
    }
    __syncthreads();
#pragma unroll
    for (int i = 0; i < 4; ++i) {
      int flat = i * 1024 + tid * 4;
      int l = flat >> 6, nn = flat & 63;
      float4 st = { Va[nn][l], Va[nn+1][l], Va[nn+2][l], Va[nn+3][l] };
      *(float4*)&VsT[(size_t)c * 65536 + (size_t)l * 1024 + n0 + nn] = st;
    }
    float acc[4][4];
#pragma unroll
    for (int i = 0; i < 4; ++i)
#pragma unroll
      for (int j = 0; j < 4; ++j) acc[i][j] = 0.f;
#pragma unroll 4
    for (int l = 0; l < 64; ++l) {
      float av[4], bv[4];
#pragma unroll
      for (int i = 0; i < 4; ++i) av[i] = Va[rg * 4 + i][l];
#pragma unroll
      for (int j = 0; j < 4; ++j) bv[j] = Bs[l][cg * 4 + j];
#pragma unroll
      for (int i = 0; i < 4; ++i)
#pragma unroll
        for (int j = 0; j < 4; ++j) acc[i][j] += av[i] * bv[j];
    }
#pragma unroll
    for (int j = 0; j < 4; ++j) {
      float4 st = { acc[0][j], acc[1][j], acc[2][j], acc[3][j] };
      *(float4*)&VaBt[(size_t)c * 65536 + (size_t)(cg * 4 + j) * 1024 + n0 + rg * 4] = st;
    }
  }
}

// K5: big_w3 (h2 read from global, 2-way k-split)
__global__ __launch_bounds__(256) void big_w3c(
    const float* __restrict__ h2, const float* __restrict__ fW3,
    const float* __restrict__ fb3, float* __restrict__ Xr)
{
  int tid = threadIdx.x;
  __shared__ float h2s[2048];
  __shared__ float sm[4][128];
  for (int i = tid; i < 2048; i += 256) h2s[i] = h2[i];
  int col = tid & 127, ks = tid >> 7;
  int j = blockIdx.x * 128 + col;
  int kbase = ks << 8;
  __syncthreads();
  float acc0 = 0.f, acc1 = 0.f, acc2 = 0.f, acc3 = 0.f;
  for (int k0 = 0; k0 < 256; k0 += 16) {
    float w[16];
#pragma unroll
    for (int u = 0; u < 16; ++u) w[u] = fW3[(size_t)(kbase + k0 + u) * 65536 + j];
#pragma unroll
    for (int u = 0; u < 16; ++u) {
      int k = kbase + k0 + u;
      acc0 += h2s[k]        * w[u];
      acc1 += h2s[512 + k]  * w[u];
      acc2 += h2s[1024 + k] * w[u];
      acc3 += h2s[1536 + k] * w[u];
    }
  }
  if (ks) { sm[0][col] = acc0; sm[1][col] = acc1; sm[2][col] = acc2; sm[3][col] = acc3; }
  __syncthreads();
  if (!ks) {
    float b = fb3[j];
    Xr[j]            = acc0 + sm[0][col] + b;
    Xr[65536 + j]    = acc1 + sm[1][col] + b;
    Xr[131072 + j]   = acc2 + sm[2][col] + b;
    Xr[196608 + j]   = acc3 + sm[3][col] + b;
  }
}

// split-flash attention partial; register softmax, St aliases VbT
template<int NSPLIT>
__global__ __launch_bounds__(256) void attn_partial(
    const float* __restrict__ VaBt, const float* __restrict__ VsT,
    const float* __restrict__ Xbase, float* __restrict__ Pl,
    float* __restrict__ ml, Pairs pr)
{
  constexpr int TILES = 16 / NSPLIT;
  int pi  = blockIdx.x / (16 * NSPLIT);
  int rem = blockIdx.x % (16 * NSPLIT);
  int nb  = rem / NSPLIT;
  int s   = rem % NSPLIT;
  int n0  = nb << 6;
  int tid = threadIdx.x;
  int rg = tid >> 4, cg = tid & 15;
  int rg4 = rg * 4, cg4 = cg * 4;
  int a = pr.a[pi], b = pr.b[pi], t = pr.t[pi];

  __shared__ __align__(16) float VaT[64][68];
  __shared__ __align__(16) float VbT[64][68];
  __shared__ __align__(16) float Xs[64][68];
  float (*St)[68] = VbT;

#pragma unroll
  for (int i = 0; i < 4; ++i) {
    int flat = i * 1024 + tid * 4;
    int p = flat >> 6, nn = flat & 63;
    float4 v = *(const float4*)&VaBt[(size_t)a * 65536 + (size_t)p * 1024 + n0 + nn];
    *(float4*)&VaT[p][nn] = v;
  }
  float m_run[4], l_run[4];
#pragma unroll
  for (int i = 0; i < 4; ++i) { m_run[i] = -1e30f; l_run[i] = 0.f; }
  float P[4][4];
#pragma unroll
  for (int i = 0; i < 4; ++i)
#pragma unroll
    for (int j = 0; j < 4; ++j) P[i][j] = 0.f;
  __syncthreads();

  for (int ti = 0; ti < TILES; ++ti) {
    int q0 = (s * TILES + ti) << 6;
    if (ti) __syncthreads();
#pragma unroll
    for (int i = 0; i < 4; ++i) {
      int flat = i * 1024 + tid * 4;
      int p = flat >> 6, qq = flat & 63;
      float4 v = *(const float4*)&VsT[(size_t)b * 65536 + (size_t)p * 1024 + q0 + qq];
      *(float4*)&VbT[p][qq] = v;
      float4 x = *(const float4*)&Xbase[(size_t)t * 65536 + (size_t)(q0 + p) * 64 + qq];
      *(float4*)&Xs[p][qq] = x;
    }
    __syncthreads();
    float sa[4][4];
#pragma unroll
    for (int i = 0; i < 4; ++i)
#pragma unroll
      for (int j = 0; j < 4; ++j) sa[i][j] = 0.f;
#pragma unroll 4
    for (int p = 0; p < 64; ++p) {
      float av[4], bv[4];
      *(float4*)av = *(const float4*)&VaT[p][rg4];
      *(float4*)bv = *(const float4*)&VbT[p][cg4];
#pragma unroll
      for (int i = 0; i < 4; ++i)
#pragma unroll
        for (int j = 0; j < 4; ++j) sa[i][j] += av[i] * bv[j];
    }
    float scv[4];
#pragma unroll
    for (int i = 0; i < 4; ++i) {
#pragma unroll
      for (int j = 0; j < 4; ++j) sa[i][j] = (sa[i][j] >= DELTA_C) ? sa[i][j] : 0.f;
      float tm = fmaxf(fmaxf(sa[i][0], sa[i][1]), fmaxf(sa[i][2], sa[i][3]));
      tm = fmaxf(tm, __shfl_xor(tm, 1));
      tm = fmaxf(tm, __shfl_xor(tm, 2));
      tm = fmaxf(tm, __shfl_xor(tm, 4));
      tm = fmaxf(tm, __shfl_xor(tm, 8));
      float mnew = fmaxf(m_run[i], tm);
      float sc = __expf(m_run[i] - mnew);
      float ssum = 0.f;
#pragma unroll
      for (int j = 0; j < 4; ++j) {
        float e = __expf(sa[i][j] - mnew);
        sa[i][j] = e;
        ssum += e;
      }
      ssum += __shfl_xor(ssum, 1);
      ssum += __shfl_xor(ssum, 2);
      ssum += __shfl_xor(ssum, 4);
      ssum += __shfl_xor(ssum, 8);
      l_run[i] = l_run[i] * sc + ssum;
      m_run[i] = mnew;
      scv[i] = sc;
    }
    __syncthreads();
#pragma unroll
    for (int i = 0; i < 4; ++i) {
      float4 e4 = { sa[i][0], sa[i][1], sa[i][2], sa[i][3] };
      *(float4*)&St[rg4 + i][cg4] = e4;
    }
    __syncthreads();
#pragma unroll
    for (int i = 0; i < 4; ++i)
#pragma unroll
      for (int j = 0; j < 4; ++j) P[i][j] *= scv[i];
#pragma unroll 2
    for (int q4 = 0; q4 < 64; q4 += 4) {
      float4 ev[4], xv[4];
#pragma unroll
      for (int i = 0; i < 4; ++i) ev[i] = *(const float4*)&St[rg4 + i][q4];
#pragma unroll
      for (int u = 0; u < 4; ++u) xv[u] = *(const float4*)&Xs[q4 + u][cg4];
#pragma unroll
      for (int i = 0; i < 4; ++i) {
        const float* e = &ev[i].x;
#pragma unroll
        for (int u = 0; u < 4; ++u) {
          const float* x = &xv[u].x;
#pragma unroll
          for (int j = 0; j < 4; ++j) P[i][j] += e[u] * x[j];
        }
      }
    }
  }
  size_t base = (size_t)((pi * 16 + nb) * NSPLIT + s);
  float* pp = Pl + base * 4096;
#pragma unroll
  for (int i = 0; i < 4; ++i) {
    float4 st = { P[i][0], P[i][1], P[i][2], P[i][3] };
    *(float4*)&pp[(size_t)(rg4 + i) * 64 + cg4] = st;
  }
  if ((tid & 15) == 0) {
    float* mlp = ml + base * 128;
#pragma unroll
    for (int i = 0; i < 4; ++i) {
      mlp[rg4 + i]      = m_run[i];
      mlp[64 + rg4 + i] = l_run[i];
    }
  }
}

// merge: block = (mm, nb, n-quarter, inst); 16 rows each -> Gp
template<int NS_T>
__global__ __launch_bounds__(256) void merge_partial16(
    const float* __restrict__ Pl, const float* __restrict__ ml,
    const float* __restrict__ Wf, const float* __restrict__ Wb,
    float* __restrict__ Gp)
{
  int mm  = blockIdx.x / 192;
  int rem = blockIdx.x % 192;
  int nb  = rem / 12;
  int r2  = rem % 12;
  int nq  = r2 / 3, inst = r2 % 3;
  int tid = threadIdx.x;
  int r = tid >> 4, fq = tid & 15;

  __shared__ __align__(16) float Ps[16][68];   // [r][f]
  __shared__ __align__(16) float Wt[64][68];   // [f][out]

  size_t base = (size_t)((mm * 3 + inst) * 16 + nb) * NS_T;
  const float* mlp = ml + base * 128;
  int rowi = nq * 16 + r;
  float mg = -1e30f;
#pragma unroll
  for (int s2 = 0; s2 < NS_T; ++s2) mg = fmaxf(mg, mlp[s2 * 128 + rowi]);
  float acc[4] = {0.f, 0.f, 0.f, 0.f};
  float lg = 0.f;
#pragma unroll
  for (int s2 = 0; s2 < NS_T; ++s2) {
    float f = __expf(mlp[s2 * 128 + rowi] - mg);
    lg += f * mlp[s2 * 128 + 64 + rowi];
    float4 v = *(const float4*)(Pl + (base + s2) * 4096 + rowi * 64 + fq * 4);
    acc[0] += f * v.x; acc[1] += f * v.y; acc[2] += f * v.z; acc[3] += f * v.w;
  }
  float inv = 1.f / lg;
  float4 pv = { acc[0] * inv, acc[1] * inv, acc[2] * inv, acc[3] * inv };
  *(float4*)&Ps[r][fq * 4] = pv;
  for (int i = tid; i < 4096; i += 256) {
    int rr = i >> 6, cc = i & 63;
    float w;
    if (inst == 0)      w = Wf[i] + Wb[i];
    else if (inst == 1) w = Wf[4096 + i];
    else                w = Wb[4096 + i];
    Wt[rr][cc] = w;
  }
  __syncthreads();
  float g0 = 0.f, g1 = 0.f, g2 = 0.f, g3 = 0.f;
#pragma unroll 8
  for (int f = 0; f < 64; ++f) {
    float p = Ps[r][f];
    float4 w4 = *(const float4*)&Wt[f][fq * 4];
    g0 += p * w4.x; g1 += p * w4.y; g2 += p * w4.z; g3 += p * w4.w;
  }
  float4 st = { g0, g1, g2, g3 };
  *(float4*)&Gp[(size_t)(mm * 3 + inst) * 65536 +
                (size_t)(nb * 64 + nq * 16 + r) * 64 + fq * 4] = st;
}

// Z = tanh(G0+b) + tanh(G1+G2+b)
__global__ __launch_bounds__(256) void finalize_z(
    const float* __restrict__ Gp, const float* __restrict__ bconv,
    float* __restrict__ dst0, float* __restrict__ dst1, float* __restrict__ extra1)
{
  int mm = blockIdx.x >> 4;
  int nb = blockIdx.x & 15;
  int tid = threadIdx.x;
  size_t tileOff = (size_t)(nb << 6) * 64;
  const float* g0 = Gp + (size_t)(mm * 3 + 0) * 65536 + tileOff;
  const float* g1 = Gp + (size_t)(mm * 3 + 1) * 65536 + tileOff;
  const float* g2 = Gp + (size_t)(mm * 3 + 2) * 65536 + tileOff;
  float* dst = (mm == 0) ? dst0 : dst1;
  for (int i = tid * 4; i < 4096; i += 1024) {
    float4 a = *(const float4*)&g0[i];
    float4 b = *(const float4*)&g1[i];
    float4 c = *(const float4*)&g2[i];
    int col = i & 63;
    float4 z;
    z.x = tanhf(a.x + bconv[col+0]) + tanhf(b.x + c.x + bconv[col+0]);
    z.y = tanhf(a.y + bconv[col+1]) + tanhf(b.y + c.y + bconv[col+1]);
    z.z = tanhf(a.z + bconv[col+2]) + tanhf(b.z + c.z + bconv[col+2]);
    z.w = tanhf(a.w + bconv[col+3]) + tanhf(b.w + c.w + bconv[col+3]);
    *(float4*)&dst[tileOff + i] = z;
    if (mm == 1 && extra1) *(float4*)&extra1[tileOff + i] = z;
  }
}

extern "C" void kernel_launch(void* const* d_in, const int* in_sizes, int n_in,
                              void* d_out, int out_size, void* d_ws, size_t ws_size,
                              hipStream_t stream)
{
  const float* observation   = (const float*)d_in[0];
  const float* time_features = (const float*)d_in[1];
  const float* layer_initial = (const float*)d_in[2];
  const float* sW1   = (const float*)d_in[3];
  const float* sb1   = (const float*)d_in[4];
  const float* s_ln_g = (const float*)d_in[5];
  const float* s_ln_b = (const float*)d_in[6];
  const float* sW2   = (const float*)d_in[7];
  const float* sb2   = (const float*)d_in[8];
  const float* tW1   = (const float*)d_in[9];
  const float* tb1   = (const float*)d_in[10];
  const float* t_ln_g = (const float*)d_in[11];
  const float* t_ln_b = (const float*)d_in[12];
  const float* tW2   = (const float*)d_in[13];
  const float* tb2   = (const float*)d_in[14];
  const float* Bmat  = (const float*)d_in[15];
  const float* fW1   = (const float*)d_in[16];
  const float* fb1   = (const float*)d_in[17];
  const float* f1g   = (const float*)d_in[18];
  const float* f1b   = (const float*)d_in[19];
  const float* fW2   = (const float*)d_in[20];
  const float* fb2   = (const float*)d_in[21];
  const float* f2g   = (const float*)d_in[22];
  const float* f2b   = (const float*)d_in[23];
  const float* fW3   = (const float*)d_in[24];
  const float* fb3   = (const float*)d_in[25];
  const float* Wf    = (const float*)d_in[26];
  const float* Wb    = (const float*)d_in[27];
  const float* bconv = (const float*)d_in[28];
  float* out = (float*)d_out;

  float* ws    = (float*)d_ws;
  float* Hs    = ws;                  // 16384
  float* Ht    = Hs    + 16384;       // 16384
  float* Hp    = Ht    + 16384;       // 65536
  float* Vs    = Hp    + 65536;       // 262144
  float* VsT   = Vs    + 262144;      // 262144
  float* VaBt  = VsT   + 262144;      // 262144
  float* part1 = VaBt  + 262144;      // 262144
  float* part2 = part1 + 262144;      // 32768
  float* h1    = part2 + 32768;       // 4096
  float* h2    = h1    + 4096;        // 2048
  float* Xr    = h2    + 2048;        // 262144
  float* Pl    = Xr    + 262144;      // 3,145,728 (L1, NS=8)
  float* ml    = Pl    + 3145728;     // 98,304
  float* Pl2   = ml    + 98304;       // 3,145,728 (L2, NS=16)
  float* ml2   = Pl2   + 3145728;     // 98,304
  float* Z1    = ml2   + 98304;       // 131072
  float* Gp    = Z1    + 131072;      // 393216 (6 x 65536)

  k1_heads_skinny<<<576, 256, 0, stream>>>(
      layer_initial, sW1, Hp,
      time_features, tW1, tb1, t_ln_g, t_ln_b, Ht,
      observation, fW1, part1);
  k2_headred_red1<<<68, 256, 0, stream>>>(
      Hp, sb1, s_ln_g, s_ln_b, Hs,
      part1, fb1, f1g, f1b, h1);
  k3_emb_skinny<<<288, 256, 0, stream>>>(
      Hs, Ht, sW2, sb2, tW2, tb2, Vs, h1, fW2, part2);
  k4_red2_vab<<<68, 256, 0, stream>>>(
      part2, fb2, f2g, f2b, h2, Vs, Bmat, VaBt, VsT);
  big_w3c<<<512, 256, 0, stream>>>(h2, fW3, fb3, Xr);

  // layer-1, m=30 (cols 60/61, X rows 0/1) and m=31 (cols 62/63, X rows 2/3)
  Pairs pA;
  pA.a[0]=1; pA.b[0]=1; pA.t[0]=1;   // k=0, m=30: A(61,61) @ X[61]
  pA.a[1]=0; pA.b[1]=1; pA.t[1]=0;   // k=1, m=30: A(60,61) @ X[60]
  pA.a[2]=1; pA.b[2]=0; pA.t[2]=0;   // k=1, m=30: A(61,60) @ X[60]
  pA.a[3]=3; pA.b[3]=3; pA.t[3]=3;   // k=0, m=31: A(63,63) @ X[63]
  pA.a[4]=2; pA.b[4]=3; pA.t[4]=2;   // k=1, m=31: A(62,63) @ X[62]
  pA.a[5]=3; pA.b[5]=2; pA.t[5]=2;   // k=1, m=31: A(63,62) @ X[62]
  attn_partial<8><<<6 * 16 * 8, 256, 0, stream>>>(VaBt, VsT, Xr, Pl, ml, pA);
  merge_partial16<8><<<384, 256, 0, stream>>>(Pl, ml, Wf, Wb, Gp);
  finalize_z<<<32, 256, 0, stream>>>(Gp, bconv, Z1, Z1 + 65536, out);

  // layer-2, m=15: cols 62(=2)/60(=0), X = Z1 rows {0: m30, 1: m31}; NS=16
  Pairs pB;
  pB.a[0]=2; pB.b[0]=2; pB.t[0]=1;   // k=0: A(62,62) @ X1[31]
  pB.a[1]=0; pB.b[1]=2; pB.t[1]=0;   // k=1: A(60,62) @ X1[30]
  pB.a[2]=2; pB.b[2]=0; pB.t[2]=0;   // k=1: A(62,60) @ X1[30]
  pB.a[3]=pB.a[4]=pB.a[5]=0; pB.b[3]=pB.b[4]=pB.b[5]=0; pB.t[3]=pB.t[4]=pB.t[5]=0;
  attn_partial<16><<<3 * 16 * 16, 256, 0, stream>>>(VaBt, VsT, Z1, Pl2, ml2, pB);
  merge_partial16<16><<<192, 256, 0, stream>>>(Pl2, ml2, Wf, Wb, Gp);
  finalize_z<<<16, 256, 0, stream>>>(Gp, bconv, out + 65536, nullptr, nullptr);
}